// Round 2
// baseline (301.204 us; speedup 1.0000x reference)
//
#include <hip/hip_runtime.h>
#include <math.h>

#define HH 1536
#define WW 1536
#define HWSZ (HH*WW)
#define NT 256                      // 4 waves/block -> 4 blocks/CU at VGPR<=128 (16 waves/CU)
#define NBLK ((HH*WW/4)/NT)         // 2304 blocks
#define BPX (NBLK/8)                // 288 blocks per XCD band

__device__ __forceinline__ float4 LD4(const float* __restrict__ p, int row, int idx) {
    return reinterpret_cast<const float4*>(p + row)[idx];
}

// NOTE: __launch_bounds__(NT, 4) here previously made LLVM target 8 waves/EU
// (64-VGPR budget) and spill ~30 floats/thread to scratch (WRITE_SIZE 92->312MB).
// amdgpu_waves_per_eu(4,4) pins min=max=4 waves/EU -> 128-VGPR budget, no spill.
__global__ __launch_bounds__(NT)
__attribute__((amdgpu_waves_per_eu(4, 4)))
void step_kernel(
    const float* __restrict__ phi,
    const float* __restrict__ sensory,
    const float* __restrict__ gamma,
    const float* __restrict__ alpha,
    const float* __restrict__ mixw,
    float* __restrict__ out,
    float* __restrict__ sums)
{
    // mix rows padded to 12 floats -> 48B rows, float4/float2 reads are aligned
    __shared__ float s_mix[10][12];
    __shared__ float s_red[4][10];

    const int tid = threadIdx.x;
    if (tid < 100) s_mix[tid / 10][tid % 10] = mixw[tid];
    // no barrier here: s_mix is first read after the mid-kernel __syncthreads

    // XCD-banded swizzle: blocks round-robin over 8 XCDs; give each XCD a
    // contiguous band of 288 blocks (~192 rows) so stencil row-reuse hits its own L2.
    const int b  = blockIdx.x;
    const int nb = (b & 7) * BPX + (b >> 3);

    const int lane = tid & 63;
    const int wave = tid >> 6;
    const int gw   = nb * 4 + wave;        // global wave id, 0..9215
    const int y    = gw / 6;               // row (6 waves per 1536-px row)
    const int wseg = gw - y * 6;           // wave segment within row
    const int col  = wseg * 64 + lane;     // float4 index within row
    const int x0   = col * 4;              // first pixel x of this thread

    const int ym1 = (y == 0)      ? HH - 1     : y - 1;
    const int yp1 = (y == HH - 1) ? 0          : y + 1;
    const int ym2 = (y < 2)       ? y + HH - 2 : y - 2;
    const int yp2 = (y >= HH - 2) ? y - HH + 2 : y + 2;

    const int r0  = y   * WW;
    const int rm1 = ym1 * WW;
    const int rp1 = yp1 * WW;
    const int rm2 = ym2 * WW;
    const int rp2 = yp2 * WW;

    // x halo indices, only consumed by lanes 0 / 63 (x0 multiple of 4 -> x0==0 is the only left wrap)
    const int xl1 = (x0 == 0)      ? WW - 1 : x0 - 1;
    const int xl2 = (x0 == 0)      ? WW - 2 : x0 - 2;
    const int xr1 = (x0 + 4 == WW) ? 0      : x0 + 4;
    const int xr2 = (x0 + 4 == WW) ? 1      : x0 + 5;

    // gamma/alpha: wave-uniform indices on const restrict ptr -> scalar loads
    const float g0 = gamma[0], g1 = gamma[1], g2 = gamma[2], g3 = gamma[3], g4 = gamma[4];
    const float g5 = gamma[5], g6 = gamma[6], g7 = gamma[7], g8 = gamma[8], g9 = gamma[9];
    const float a0 = alpha[0];

    float pv[10][4];   // phi values (kept for coupling)
    float dv[10][4];   // per-channel dphi (nonlinear + lap/bilap part)

    #pragma unroll
    for (int c = 0; c < 10; ++c) {
        const float* pc = phi + (size_t)c * HWSZ;
        const float4 cm = LD4(pc, r0,  col);
        const float4 nn = LD4(pc, rm1, col);
        const float4 ss = LD4(pc, rp1, col);

        // x-neighbors live in adjacent lanes' registers: shuffle instead of loading
        float wl1 = __shfl_up  (cm.w, 1, 64);
        float wr1 = __shfl_down(cm.x, 1, 64);

        const bool BI = (c == 0 || c == 3 || c == 4 || c == 9);  // compile-time (unrolled)
        float4 t2n = {0,0,0,0}, t2s = {0,0,0,0};
        float wl2 = 0.f, wr2 = 0.f, nwl = 0.f, ner = 0.f, swl = 0.f, ser = 0.f;
        if (BI) {
            t2n = LD4(pc, rm2, col);
            t2s = LD4(pc, rp2, col);
            wl2 = __shfl_up  (cm.z, 1, 64);
            wr2 = __shfl_down(cm.y, 1, 64);
            nwl = __shfl_up  (nn.w, 1, 64);
            ner = __shfl_down(nn.x, 1, 64);
            swl = __shfl_up  (ss.w, 1, 64);
            ser = __shfl_down(ss.x, 1, 64);
        }
        // wave-edge lanes fix up from memory (2 lanes active -> near-free)
        if (lane == 0) {
            wl1 = pc[r0 + xl1];
            if (BI) { wl2 = pc[r0 + xl2]; nwl = pc[rm1 + xl1]; swl = pc[rp1 + xl1]; }
        }
        if (lane == 63) {
            wr1 = pc[r0 + xr1];
            if (BI) { wr2 = pc[r0 + xr2]; ner = pc[rm1 + xr1]; ser = pc[rp1 + xr1]; }
        }

        float lap[4];
        lap[0] = nn.x + ss.x + wl1  + cm.y - 4.0f * cm.x;
        lap[1] = nn.y + ss.y + cm.x + cm.z - 4.0f * cm.y;
        lap[2] = nn.z + ss.z + cm.y + cm.w - 4.0f * cm.z;
        lap[3] = nn.w + ss.w + cm.z + wr1  - 4.0f * cm.w;

        float bl[4] = {0.f, 0.f, 0.f, 0.f};
        if (BI) {
            // direct 13-pt bilaplacian: 20c -8(N+S+W+E) +2(diag) + (NN+SS+WW+EE)
            bl[0] = 20.0f*cm.x - 8.0f*(nn.x + ss.x + wl1  + cm.y)
                  + 2.0f*(nwl  + nn.y + swl  + ss.y) + (t2n.x + t2s.x + wl2  + cm.z);
            bl[1] = 20.0f*cm.y - 8.0f*(nn.y + ss.y + cm.x + cm.z)
                  + 2.0f*(nn.x + nn.z + ss.x + ss.z) + (t2n.y + t2s.y + wl1  + cm.w);
            bl[2] = 20.0f*cm.z - 8.0f*(nn.z + ss.z + cm.y + cm.w)
                  + 2.0f*(nn.y + nn.w + ss.y + ss.w) + (t2n.z + t2s.z + cm.x + wr1);
            bl[3] = 20.0f*cm.w - 8.0f*(nn.w + ss.w + cm.z + wr1)
                  + 2.0f*(nn.z + ner  + ss.z + ser ) + (t2n.w + t2s.w + cm.y + wr2);
        }

        pv[c][0] = cm.x; pv[c][1] = cm.y; pv[c][2] = cm.z; pv[c][3] = cm.w;

        #pragma unroll
        for (int k = 0; k < 4; ++k) {
            const float pp = pv[c][k];
            const float lv = lap[k];
            const float bv = bl[k];
            float dd;
            switch (c) {
            case 0: dd = -g0*lv - a0*pp*pp*pp + 0.12f*bv; break;
            case 1: dd = -g1*lv + 0.15f*__sinf(pp) + 0.08f*pp*pp*pp; break;
            case 2: dd = -g2*lv + 0.2f*pp*(1.0f - pp*pp); break;
            case 3: { const float p2 = pp*pp;
                      dd = -g3*lv - 0.03f*p2*p2*pp + 0.08f*bv; } break;
            case 4: dd = -g4*lv + 0.12f*pp*__logf(fabsf(pp) + 1e-6f) + 0.02f*bv; break;
            case 5: { const float p2 = pp*pp;
                      dd = -g5*lv + 0.08f*p2*pp - 0.02f*p2*p2*pp; } break;
            case 6: { const float p2 = pp*pp;
                      dd = -g6*lv + 0.06f*p2*p2 - 0.04f*pp; } break;
            case 7: { const float pc7 = fminf(fmaxf(pp, -2.0f), 2.0f);
                      const float ex  = __expf(pc7);
                      const float exm = __expf(-pc7);
                      dd = -g7*lv + 0.04f*(ex - exm); } break;   // 0.08*sinh = 0.04*(e^x - e^-x)
            case 8: dd = -g8*lv + 0.05f*pp*pp - 0.08f*pp; break;
            default: { const float p3 = pp*pp*pp;
                       dd = -g9*lv + 0.02f*p3*p3 - 0.04f*p3 + 0.01f*bv; } break;
            }
            dv[c][k] = dd;
        }
    }

    float fmv[4], smv[4], sdk[4];
    {
        const float4 sd4 = LD4(sensory, r0, col);
        sdk[0] = sd4.x; sdk[1] = sd4.y; sdk[2] = sd4.z; sdk[3] = sd4.w;
        #pragma unroll
        for (int k = 0; k < 4; ++k) {
            fmv[k] = (pv[0][k] + pv[1][k] + pv[2][k] + pv[3][k] + pv[4][k]) * 0.2f;
            smv[k] = (pv[5][k] + pv[6][k] + pv[7][k] + pv[8][k] + pv[9][k]) * 0.2f;
        }
    }

    __syncthreads();   // s_mix visible before coupling reads

    #pragma unroll
    for (int o = 0; o < 10; ++o) {
        const float4 m0 = *reinterpret_cast<const float4*>(&s_mix[o][0]);
        const float4 m1 = *reinterpret_cast<const float4*>(&s_mix[o][4]);
        const float2 m2 = *reinterpret_cast<const float2*>(&s_mix[o][8]);
        float pn[4];
        #pragma unroll
        for (int k = 0; k < 4; ++k) {
            float cp;
            cp = m0.x * pv[0][k];
            cp = fmaf(m0.y, pv[1][k], cp);
            cp = fmaf(m0.z, pv[2][k], cp);
            cp = fmaf(m0.w, pv[3][k], cp);
            cp = fmaf(m1.x, pv[4][k], cp);
            cp = fmaf(m1.y, pv[5][k], cp);
            cp = fmaf(m1.z, pv[6][k], cp);
            cp = fmaf(m1.w, pv[7][k], cp);
            cp = fmaf(m2.x, pv[8][k], cp);
            cp = fmaf(m2.y, pv[9][k], cp);
            float dd = dv[o][k];
            if (o < 5) {
                dd += 0.06f * cp + 0.02f * smv[k];          // EPS_FAST, S2F
                if (o == 0) dd += 0.2f  * sdk[k];
                if (o == 4) dd += 0.08f * fabsf(sdk[k]);
                pn[k] = pv[o][k] + 0.02f * dd;              // DT * FAST_DT
            } else {
                dd += 0.02f * cp + 0.04f * fmv[k];          // EPS_SLOW, F2S
                if (o == 9) dd += 0.05f * sdk[k];
                pn[k] = pv[o][k] + 0.004f * dd;             // DT * SLOW_DT
            }
            pn[k] = fminf(fmaxf(pn[k], -4.0f), 4.0f);
        }
        float4 o4; o4.x = pn[0]; o4.y = pn[1]; o4.z = pn[2]; o4.w = pn[3];
        reinterpret_cast<float4*>(out + (size_t)o * HWSZ + r0)[col] = o4;

        float s = pn[0] + pn[1] + pn[2] + pn[3];
        #pragma unroll
        for (int off = 32; off > 0; off >>= 1) s += __shfl_down(s, off, 64);
        if (lane == 0) s_red[wave][o] = s;
    }

    __syncthreads();
    if (tid < 10) {
        float v = s_red[0][tid] + s_red[1][tid] + s_red[2][tid] + s_red[3][tid];
        atomicAdd(&sums[tid], v);
    }
}

__global__ void finalize_kernel(const float* __restrict__ sums,
                                float* __restrict__ out)
{
    const int t = threadIdx.x;
    const float inv = 1.0f / (float)HWSZ;
    const size_t base = (size_t)10 * HWSZ;
    if (t == 0) out[base]     = sums[0] * inv;  // phi1_mean (channel 0)
    if (t == 1) out[base + 1] = sums[4] * inv;  // phi5_mean (channel 4)
    if (t >= 2 && t < 12) out[base + 2 + (t - 2)] = sums[t - 2] * inv;  // field_means
}

extern "C" void kernel_launch(void* const* d_in, const int* in_sizes, int n_in,
                              void* d_out, int out_size, void* d_ws, size_t ws_size,
                              hipStream_t stream) {
    const float* phi     = (const float*)d_in[0];
    const float* sensory = (const float*)d_in[1];
    const float* gamma   = (const float*)d_in[2];
    const float* alpha   = (const float*)d_in[3];
    const float* mixw    = (const float*)d_in[4];
    float* out = (float*)d_out;
    float* sums = (float*)d_ws;

    hipMemsetAsync(sums, 0, 10 * sizeof(float), stream);

    step_kernel<<<dim3(NBLK), NT, 0, stream>>>(phi, sensory, gamma, alpha, mixw, out, sums);
    finalize_kernel<<<1, 64, 0, stream>>>(sums, out);
}

// Round 3
// 267.540 us; speedup vs baseline: 1.1258x; 1.1258x over previous
//
#include <hip/hip_runtime.h>
#include <math.h>

#define HH 1536
#define WW 1536
#define HWSZ (HH*WW)
#define NT 384      // one row per block: 384 threads x 4 px = 1536. 6 waves/block.
#define NBLK HH

// NOTE on register budget (rounds 1-2 lesson): with 256-thread blocks the
// allocator targets 8 waves/EU (64 VGPR) and spills ~23 floats/thread to
// scratch (WRITE_SIZE 92->312MB); amdgpu_waves_per_eu(4,4) did NOT override.
// The 384-thread / one-row-per-block framing reliably gets 112 VGPR, no spill.

__device__ __forceinline__ float4 LD4(const float* __restrict__ p, int row, int t) {
    return reinterpret_cast<const float4*>(p + row)[t];
}

__global__ __launch_bounds__(NT) void step_kernel(
    const float* __restrict__ phi,
    const float* __restrict__ sensory,
    const float* __restrict__ gamma,
    const float* __restrict__ alpha,
    const float* __restrict__ mixw,
    float* __restrict__ out,
    float* __restrict__ sums)     // ws: sums[0..9], counter at sums[10]
{
    // mix rows padded to 12 floats -> 48B rows, float4/float2 reads stay aligned
    __shared__ float s_mix[10][12];
    __shared__ float s_red[6][10];

    const int tid = threadIdx.x;
    if (tid < 100) s_mix[tid / 10][tid % 10] = mixw[tid];
    // no barrier here: s_mix is first read after the mid-kernel __syncthreads

    // XCD-banded swizzle: blocks dispatch round-robin over 8 XCDs; give each
    // XCD a contiguous 192-row band so stencil row-reuse hits its own L2.
    const int blk = blockIdx.x;
    const int y = (blk & 7) * 192 + (blk >> 3);

    const int lane = tid & 63;
    const int wave = tid >> 6;
    const int x0 = tid * 4;

    const int ym1 = (y == 0)      ? HH - 1     : y - 1;
    const int yp1 = (y == HH - 1) ? 0          : y + 1;
    const int ym2 = (y < 2)       ? y + HH - 2 : y - 2;
    const int yp2 = (y >= HH - 2) ? y - HH + 2 : y + 2;

    const int r0  = y   * WW;
    const int rm1 = ym1 * WW;
    const int rp1 = yp1 * WW;
    const int rm2 = ym2 * WW;
    const int rp2 = yp2 * WW;

    // x halo indices, only consumed by edge lanes (x0 mult of 4 -> x0==0 is only left wrap)
    const int xl1 = (x0 == 0)      ? WW - 1 : x0 - 1;
    const int xl2 = (x0 == 0)      ? WW - 2 : x0 - 2;
    const int xr1 = (x0 + 4 == WW) ? 0      : x0 + 4;
    const int xr2 = (x0 + 4 == WW) ? 1      : x0 + 5;

    // gamma/alpha: wave-uniform indices on const restrict ptr -> scalar loads
    const float g0 = gamma[0], g1 = gamma[1], g2 = gamma[2], g3 = gamma[3], g4 = gamma[4];
    const float g5 = gamma[5], g6 = gamma[6], g7 = gamma[7], g8 = gamma[8], g9 = gamma[9];
    const float a0 = alpha[0];

    float pv[10][4];   // phi values (kept for coupling)
    float dv[10][4];   // per-channel dphi (nonlinear + lap/bilap part)

    #pragma unroll
    for (int c = 0; c < 10; ++c) {
        const float* pc = phi + (size_t)c * HWSZ;
        const float4 cm = LD4(pc, r0,  tid);
        const float4 nn = LD4(pc, rm1, tid);
        const float4 ss = LD4(pc, rp1, tid);

        // x-neighbors live in adjacent lanes' registers: shuffle instead of loading
        float wl1 = __shfl_up  (cm.w, 1, 64);
        float wr1 = __shfl_down(cm.x, 1, 64);

        const bool BI = (c == 0 || c == 3 || c == 4 || c == 9);  // compile-time (unrolled)
        float4 t2n = {0,0,0,0}, t2s = {0,0,0,0};
        float wl2 = 0.f, wr2 = 0.f, nwl = 0.f, ner = 0.f, swl = 0.f, ser = 0.f;
        if (BI) {
            t2n = LD4(pc, rm2, tid);
            t2s = LD4(pc, rp2, tid);
            wl2 = __shfl_up  (cm.z, 1, 64);
            wr2 = __shfl_down(cm.y, 1, 64);
            nwl = __shfl_up  (nn.w, 1, 64);
            ner = __shfl_down(nn.x, 1, 64);
            swl = __shfl_up  (ss.w, 1, 64);
            ser = __shfl_down(ss.x, 1, 64);
        }
        // wave-edge lanes fix up from memory (2 of 64 lanes active -> near-free)
        if (lane == 0) {
            wl1 = pc[r0 + xl1];
            if (BI) { wl2 = pc[r0 + xl2]; nwl = pc[rm1 + xl1]; swl = pc[rp1 + xl1]; }
        }
        if (lane == 63) {
            wr1 = pc[r0 + xr1];
            if (BI) { wr2 = pc[r0 + xr2]; ner = pc[rm1 + xr1]; ser = pc[rp1 + xr1]; }
        }

        float lap[4];
        lap[0] = nn.x + ss.x + wl1  + cm.y - 4.0f * cm.x;
        lap[1] = nn.y + ss.y + cm.x + cm.z - 4.0f * cm.y;
        lap[2] = nn.z + ss.z + cm.y + cm.w - 4.0f * cm.z;
        lap[3] = nn.w + ss.w + cm.z + wr1  - 4.0f * cm.w;

        float bl[4] = {0.f, 0.f, 0.f, 0.f};
        if (BI) {
            // direct 13-pt bilaplacian: 20c -8(N+S+W+E) +2(diag) + (NN+SS+WW+EE)
            bl[0] = 20.0f*cm.x - 8.0f*(nn.x + ss.x + wl1  + cm.y)
                  + 2.0f*(nwl  + nn.y + swl  + ss.y) + (t2n.x + t2s.x + wl2  + cm.z);
            bl[1] = 20.0f*cm.y - 8.0f*(nn.y + ss.y + cm.x + cm.z)
                  + 2.0f*(nn.x + nn.z + ss.x + ss.z) + (t2n.y + t2s.y + wl1  + cm.w);
            bl[2] = 20.0f*cm.z - 8.0f*(nn.z + ss.z + cm.y + cm.w)
                  + 2.0f*(nn.y + nn.w + ss.y + ss.w) + (t2n.z + t2s.z + cm.x + wr1);
            bl[3] = 20.0f*cm.w - 8.0f*(nn.w + ss.w + cm.z + wr1)
                  + 2.0f*(nn.z + ner  + ss.z + ser ) + (t2n.w + t2s.w + cm.y + wr2);
        }

        pv[c][0] = cm.x; pv[c][1] = cm.y; pv[c][2] = cm.z; pv[c][3] = cm.w;

        #pragma unroll
        for (int k = 0; k < 4; ++k) {
            const float pp = pv[c][k];
            const float lv = lap[k];
            const float bv = bl[k];
            float dd;
            switch (c) {
            case 0: dd = -g0*lv - a0*pp*pp*pp + 0.12f*bv; break;
            case 1: dd = -g1*lv + 0.15f*__sinf(pp) + 0.08f*pp*pp*pp; break;
            case 2: dd = -g2*lv + 0.2f*pp*(1.0f - pp*pp); break;
            case 3: { const float p2 = pp*pp;
                      dd = -g3*lv - 0.03f*p2*p2*pp + 0.08f*bv; } break;
            case 4: dd = -g4*lv + 0.12f*pp*__logf(fabsf(pp) + 1e-6f) + 0.02f*bv; break;
            case 5: { const float p2 = pp*pp;
                      dd = -g5*lv + 0.08f*p2*pp - 0.02f*p2*p2*pp; } break;
            case 6: { const float p2 = pp*pp;
                      dd = -g6*lv + 0.06f*p2*p2 - 0.04f*pp; } break;
            case 7: { const float pc7 = fminf(fmaxf(pp, -2.0f), 2.0f);
                      const float ex  = __expf(pc7);
                      const float exm = __expf(-pc7);
                      dd = -g7*lv + 0.04f*(ex - exm); } break;   // 0.08*sinh = 0.04*(e^x - e^-x)
            case 8: dd = -g8*lv + 0.05f*pp*pp - 0.08f*pp; break;
            default: { const float p3 = pp*pp*pp;
                       dd = -g9*lv + 0.02f*p3*p3 - 0.04f*p3 + 0.01f*bv; } break;
            }
            dv[c][k] = dd;
        }
    }

    float fmv[4], smv[4], sdk[4];
    {
        const float4 sd4 = LD4(sensory, r0, tid);
        sdk[0] = sd4.x; sdk[1] = sd4.y; sdk[2] = sd4.z; sdk[3] = sd4.w;
        #pragma unroll
        for (int k = 0; k < 4; ++k) {
            fmv[k] = (pv[0][k] + pv[1][k] + pv[2][k] + pv[3][k] + pv[4][k]) * 0.2f;
            smv[k] = (pv[5][k] + pv[6][k] + pv[7][k] + pv[8][k] + pv[9][k]) * 0.2f;
        }
    }

    __syncthreads();   // s_mix visible before coupling reads

    #pragma unroll
    for (int o = 0; o < 10; ++o) {
        const float4 m0 = *reinterpret_cast<const float4*>(&s_mix[o][0]);
        const float4 m1 = *reinterpret_cast<const float4*>(&s_mix[o][4]);
        const float2 m2 = *reinterpret_cast<const float2*>(&s_mix[o][8]);
        float pn[4];
        #pragma unroll
        for (int k = 0; k < 4; ++k) {
            float cp;
            cp = m0.x * pv[0][k];
            cp = fmaf(m0.y, pv[1][k], cp);
            cp = fmaf(m0.z, pv[2][k], cp);
            cp = fmaf(m0.w, pv[3][k], cp);
            cp = fmaf(m1.x, pv[4][k], cp);
            cp = fmaf(m1.y, pv[5][k], cp);
            cp = fmaf(m1.z, pv[6][k], cp);
            cp = fmaf(m1.w, pv[7][k], cp);
            cp = fmaf(m2.x, pv[8][k], cp);
            cp = fmaf(m2.y, pv[9][k], cp);
            float dd = dv[o][k];
            if (o < 5) {
                dd += 0.06f * cp + 0.02f * smv[k];          // EPS_FAST, S2F
                if (o == 0) dd += 0.2f  * sdk[k];
                if (o == 4) dd += 0.08f * fabsf(sdk[k]);
                pn[k] = pv[o][k] + 0.02f * dd;              // DT * FAST_DT
            } else {
                dd += 0.02f * cp + 0.04f * fmv[k];          // EPS_SLOW, F2S
                if (o == 9) dd += 0.05f * sdk[k];
                pn[k] = pv[o][k] + 0.004f * dd;             // DT * SLOW_DT
            }
            pn[k] = fminf(fmaxf(pn[k], -4.0f), 4.0f);
        }
        float4 o4; o4.x = pn[0]; o4.y = pn[1]; o4.z = pn[2]; o4.w = pn[3];
        reinterpret_cast<float4*>(out + (size_t)o * HWSZ + r0)[tid] = o4;

        float s = pn[0] + pn[1] + pn[2] + pn[3];
        #pragma unroll
        for (int off = 32; off > 0; off >>= 1) s += __shfl_down(s, off, 64);
        if (lane == 0) s_red[wave][o] = s;
    }

    __syncthreads();
    if (tid < 10) {
        float v = 0.0f;
        #pragma unroll
        for (int w = 0; w < 6; ++w) v += s_red[w][tid];
        atomicAdd(&sums[tid], v);
    }

    // Fused finalize: barrier drains this block's atomics (waitcnt before
    // s_barrier), then last-done block reads the totals coherently and writes
    // the 12 scalar outputs. Saves one dispatch.
    __syncthreads();
    if (tid == 0) {
        __threadfence();
        unsigned int* cnt = reinterpret_cast<unsigned int*>(sums + 10);
        const unsigned int old = atomicAdd(cnt, 1u);
        if (old == (unsigned int)(NBLK - 1)) {
            const float inv = 1.0f / (float)HWSZ;
            const size_t base = (size_t)10 * HWSZ;
            float sv[10];
            #pragma unroll
            for (int i = 0; i < 10; ++i) sv[i] = atomicAdd(&sums[i], 0.0f);  // coherent read
            out[base]     = sv[0] * inv;                     // phi1_mean (channel 0)
            out[base + 1] = sv[4] * inv;                     // phi5_mean (channel 4)
            #pragma unroll
            for (int i = 0; i < 10; ++i) out[base + 2 + i] = sv[i] * inv;  // field_means
        }
    }
}

extern "C" void kernel_launch(void* const* d_in, const int* in_sizes, int n_in,
                              void* d_out, int out_size, void* d_ws, size_t ws_size,
                              hipStream_t stream) {
    const float* phi     = (const float*)d_in[0];
    const float* sensory = (const float*)d_in[1];
    const float* gamma   = (const float*)d_in[2];
    const float* alpha   = (const float*)d_in[3];
    const float* mixw    = (const float*)d_in[4];
    float* out = (float*)d_out;
    float* sums = (float*)d_ws;

    hipMemsetAsync(sums, 0, 11 * sizeof(float), stream);   // 10 sums + done-counter

    step_kernel<<<dim3(NBLK), NT, 0, stream>>>(phi, sensory, gamma, alpha, mixw, out, sums);
}